// Round 2
// baseline (372.666 us; speedup 1.0000x reference)
//
#include <hip/hip_runtime.h>
#include <math.h>

#define TILE 64

typedef float v4f  __attribute__((ext_vector_type(4)));
typedef float v4fu __attribute__((ext_vector_type(4), aligned(4)));  // 4B-aligned source loads

// One block per 64x64 tile of the upper triangle (incl. diagonal), 1D triangular grid.
// Off-diag: 4x float4 comp loads (all in flight) -> NT float4 upper stores + LDS ->
// transposed NT float4 lower stores. Diag: scalar predicated path (128 blocks only).
__global__ __launch_bounds__(256) void uncompress_sym_kernel(
    const float* __restrict__ comp, float* __restrict__ out, int n, int T) {
    // Decode linear block id -> (tr, tc), tc >= tr. Row tr holds (T - tr) tiles;
    // cumulative count before tr is S(tr) = tr*T - tr*(tr-1)/2.
    const int b = blockIdx.x;
    int tr = (int)((2 * T + 1 - sqrtf((float)((2 * T + 1) * (2 * T + 1) - 8 * b))) * 0.5f);
    while (tr * T - tr * (tr - 1) / 2 > b) --tr;                    // float fixup (scalar, uniform)
    while ((tr + 1) * T - (tr + 1) * tr / 2 <= b) ++tr;
    const int tc = tr + (b - (tr * T - tr * (tr - 1) / 2));

    const int tid = threadIdx.x;
    __shared__ float s[TILE][TILE + 1];  // +1: odd stride -> conflict-free transpose

    const int i0 = tr * TILE;
    const int j0 = tc * TILE;

    if (tr != tc) {
        const int x4 = (tid & 15) * 4;      // col offset within tile (16B-aligned in out)
        const int yb = tid >> 4;            // base row (0..15), +16 per iteration
        // Phase 1: all 4 loads in flight before any use.
        v4f v[4];
#pragma unroll
        for (int it = 0; it < 4; ++it) {
            const int i = i0 + yb + it * 16;
            const int base = i * (2 * n - i - 1) / 2 - i - 1;   // comp idx = base + j (i<j)
            v[it] = *(const v4fu*)&comp[base + j0 + x4];
        }
        // Phase 2: NT upper stores + LDS stage.
#pragma unroll
        for (int it = 0; it < 4; ++it) {
            const int y = yb + it * 16;
            __builtin_nontemporal_store(v[it], (v4f*)&out[(size_t)(i0 + y) * n + (j0 + x4)]);
            s[y][x4 + 0] = v[it].x;
            s[y][x4 + 1] = v[it].y;
            s[y][x4 + 2] = v[it].z;
            s[y][x4 + 3] = v[it].w;
        }
        __syncthreads();
        // Phase 3: transposed NT lower stores: out[j][i] = s[i-i0][j-j0].
#pragma unroll
        for (int it = 0; it < 4; ++it) {
            const int y = yb + it * 16;
            v4f w;
            w.x = s[x4 + 0][y];  // stride-65: banks differ per lane, <=2-way (free)
            w.y = s[x4 + 1][y];
            w.z = s[x4 + 2][y];
            w.w = s[x4 + 3][y];
            __builtin_nontemporal_store(w, (v4f*)&out[(size_t)(j0 + y) * n + (i0 + x4)]);
        }
    } else {
        // Diagonal tile: strict upper from comp, diag = 1, lower mirrored in-tile.
        for (int e = tid; e < TILE * TILE; e += 256) {
            const int y = e >> 6;
            const int x = e & 63;
            float v = 0.0f;
            if (x > y) {
                const int i = i0 + y;
                const int base = i * (2 * n - i - 1) / 2 - i - 1;
                v = comp[base + j0 + x];
            }
            s[y][x] = v;
        }
        __syncthreads();
        for (int e = tid; e < TILE * TILE; e += 256) {
            const int y = e >> 6;
            const int x = e & 63;
            float v;
            if (x > y)       v = s[y][x];
            else if (x == y) v = 1.0f;
            else             v = s[x][y];
            __builtin_nontemporal_store(v, &out[(size_t)(i0 + y) * n + (j0 + x)]);
        }
    }
}

extern "C" void kernel_launch(void* const* d_in, const int* in_sizes, int n_in,
                              void* d_out, int out_size, void* d_ws, size_t ws_size,
                              hipStream_t stream) {
    const float* comp = (const float*)d_in[0];
    float* out = (float*)d_out;
    const long long m = in_sizes[0];
    const int n = (int)llround(sqrt(2.0 * (double)m)) + 1;  // 8192
    const int T = n / TILE;                                 // 128
    const int nblocks = T * (T + 1) / 2;                    // 8256 (upper triangle incl. diag)
    uncompress_sym_kernel<<<nblocks, 256, 0, stream>>>(comp, out, n, T);
}

// Round 3
// 369.714 us; speedup vs baseline: 1.0080x; 1.0080x over previous
//
#include <hip/hip_runtime.h>
#include <math.h>

#define TILE 64

typedef float v4f  __attribute__((ext_vector_type(4)));
typedef float v4fu __attribute__((ext_vector_type(4), aligned(4)));  // 4B-aligned source loads

// One block per 64x64 tile of the upper triangle (incl. diagonal), 1D triangular grid.
// Block-id swizzle groups 1032 consecutive tiles per XCD (dispatch round-robins
// blockIdx % 8 across XCDs) so comp cache lines shared by horizontally adjacent
// tiles are fetched into one L2, not two.
__global__ __launch_bounds__(256) void uncompress_sym_kernel(
    const float* __restrict__ comp, float* __restrict__ out, int n, int T) {
    // XCD-grouping swizzle: nblocks = 8256 = 8 * 1032 exactly.
    const int b = (blockIdx.x & 7) * 1032 + (blockIdx.x >> 3);
    // Decode linear tile id -> (tr, tc), tc >= tr. Cumulative before tr: tr*T - tr*(tr-1)/2.
    int tr = (int)((2 * T + 1 - sqrtf((float)((2 * T + 1) * (2 * T + 1) - 8 * b))) * 0.5f);
    while (tr * T - tr * (tr - 1) / 2 > b) --tr;                    // float fixup (uniform)
    while ((tr + 1) * T - (tr + 1) * tr / 2 <= b) ++tr;
    const int tc = tr + (b - (tr * T - tr * (tr - 1) / 2));

    const int tid = threadIdx.x;
    __shared__ float s[TILE][TILE + 1];  // +1: odd stride -> conflict-free transpose

    const int i0 = tr * TILE;
    const int j0 = tc * TILE;

    if (tr != tc) {
        const int x4 = (tid & 15) * 4;      // col offset within tile (16B-aligned in out)
        const int yb = tid >> 4;            // base row (0..15), +16 per iteration
        // Phase 1: all 4 loads in flight before any use.
        v4f v[4];
#pragma unroll
        for (int it = 0; it < 4; ++it) {
            const int i = i0 + yb + it * 16;
            const int base = i * (2 * n - i - 1) / 2 - i - 1;   // comp idx = base + j (i<j)
            v[it] = *(const v4fu*)&comp[base + j0 + x4];
        }
        // Phase 2: NT upper stores + LDS stage.
#pragma unroll
        for (int it = 0; it < 4; ++it) {
            const int y = yb + it * 16;
            __builtin_nontemporal_store(v[it], (v4f*)&out[(size_t)(i0 + y) * n + (j0 + x4)]);
            s[y][x4 + 0] = v[it].x;
            s[y][x4 + 1] = v[it].y;
            s[y][x4 + 2] = v[it].z;
            s[y][x4 + 3] = v[it].w;
        }
        __syncthreads();
        // Phase 3: transposed NT lower stores: out[j][i] = s[i-i0][j-j0].
#pragma unroll
        for (int it = 0; it < 4; ++it) {
            const int y = yb + it * 16;
            v4f w;
            w.x = s[x4 + 0][y];  // stride-65: <=2-way bank aliasing (free per m136)
            w.y = s[x4 + 1][y];
            w.z = s[x4 + 2][y];
            w.w = s[x4 + 3][y];
            __builtin_nontemporal_store(w, (v4f*)&out[(size_t)(j0 + y) * n + (i0 + x4)]);
        }
    } else {
        // Diagonal tile: strict upper from comp, diag = 1, lower mirrored in-tile.
        for (int e = tid; e < TILE * TILE; e += 256) {
            const int y = e >> 6;
            const int x = e & 63;
            float v = 0.0f;
            if (x > y) {
                const int i = i0 + y;
                const int base = i * (2 * n - i - 1) / 2 - i - 1;
                v = comp[base + j0 + x];
            }
            s[y][x] = v;
        }
        __syncthreads();
        for (int e = tid; e < TILE * TILE; e += 256) {
            const int y = e >> 6;
            const int x = e & 63;
            float v;
            if (x > y)       v = s[y][x];
            else if (x == y) v = 1.0f;
            else             v = s[x][y];
            __builtin_nontemporal_store(v, &out[(size_t)(i0 + y) * n + (j0 + x)]);
        }
    }
}

extern "C" void kernel_launch(void* const* d_in, const int* in_sizes, int n_in,
                              void* d_out, int out_size, void* d_ws, size_t ws_size,
                              hipStream_t stream) {
    const float* comp = (const float*)d_in[0];
    float* out = (float*)d_out;
    const long long m = in_sizes[0];
    const int n = (int)llround(sqrt(2.0 * (double)m)) + 1;  // 8192
    const int T = n / TILE;                                 // 128
    const int nblocks = T * (T + 1) / 2;                    // 8256 = 8 * 1032
    uncompress_sym_kernel<<<nblocks, 256, 0, stream>>>(comp, out, n, T);
}